// Round 12
// baseline (616.963 us; speedup 1.0000x reference)
//
#include <hip/hip_runtime.h>
#include <math.h>

#define NXD 256
#define NYD 256
#define NZD 64
#define NCELL (NXD*NYD)

typedef __bf16 bf16x8 __attribute__((ext_vector_type(8)));
typedef float f32x4 __attribute__((ext_vector_type(4)));

// ---------------- small utils ----------------
__global__ __launch_bounds__(64) void zero_k(int* p) { p[threadIdx.x] = 0; }

__global__ __launch_bounds__(256) void f2bf_k(const float* __restrict__ in,
                                              __bf16* __restrict__ out, int n) {
    int i = blockIdx.x * 256 + threadIdx.x;
    if (i < n) out[i] = (__bf16)in[i];
}

// ================= spatial sort (stream compaction of table) ===================
__global__ __launch_bounds__(256) void count_k(const int* __restrict__ table,
                                               int* __restrict__ partial) {
    __shared__ int red[4];
    int tid = threadIdx.x, lane = tid & 63, wid = tid >> 6;
    int4 v = *(const int4*)(table + blockIdx.x * 1024 + tid * 4);
    int c = (v.x > 0) + (v.y > 0) + (v.z > 0) + (v.w > 0);
    for (int d = 32; d; d >>= 1) c += __shfl_down(c, d, 64);
    if (lane == 0) red[wid] = c;
    __syncthreads();
    if (tid == 0) partial[blockIdx.x] = red[0] + red[1] + red[2] + red[3];
}

__global__ __launch_bounds__(1024) void scan_k(const int* __restrict__ partial,
                                               int* __restrict__ scanned) {
    __shared__ int wsum[16];
    int tid = threadIdx.x, lane = tid & 63, wid = tid >> 6;
    int4 v = ((const int4*)partial)[tid];
    int tot = v.x + v.y + v.z + v.w;
    int sc = tot;
    for (int d = 1; d < 64; d <<= 1) { int o = __shfl_up(sc, d, 64); if (lane >= d) sc += o; }
    if (lane == 63) wsum[wid] = sc;
    __syncthreads();
    int wbase = 0;
    for (int w = 0; w < 16; ++w) if (w < wid) wbase += wsum[w];
    int excl = wbase + sc - tot;
    int4 o4;
    o4.x = excl; o4.y = excl + v.x; o4.z = excl + v.x + v.y; o4.w = excl + v.x + v.y + v.z;
    ((int4*)scanned)[tid] = o4;
}

__global__ __launch_bounds__(256) void emit_k(const int* __restrict__ table,
        const int* __restrict__ scanned, int* __restrict__ table2,
        int* __restrict__ perm, int4* __restrict__ coords) {
    __shared__ int wsum[4];
    int tid = threadIdx.x, lane = tid & 63, wid = tid >> 6;
    int gbase = blockIdx.x * 1024 + tid * 4;
    int4 v = *(const int4*)(table + gbase);
    int vals[4] = {v.x, v.y, v.z, v.w};
    int c = (v.x > 0) + (v.y > 0) + (v.z > 0) + (v.w > 0);
    int sc = c;
    for (int d = 1; d < 64; d <<= 1) { int o = __shfl_up(sc, d, 64); if (lane >= d) sc += o; }
    if (lane == 63) wsum[wid] = sc;
    __syncthreads();
    int wbase = 0;
    for (int w = 0; w < 4; ++w) if (w < wid) wbase += wsum[w];
    int pos = scanned[blockIdx.x] + wbase + sc - c;
    int t2[4];
    #pragma unroll
    for (int j = 0; j < 4; ++j) {
        int flat = gbase + j;
        if (vals[j] > 0) {
            t2[j] = pos + 1;
            perm[pos] = vals[j] - 1;
            coords[pos] = make_int4(0, flat >> 14, (flat >> 6) & 255, flat & 63);
            ++pos;
        } else t2[j] = 0;
    }
    *(int4*)(table2 + gbase) = make_int4(t2[0], t2[1], t2[2], t2[3]);
}

__global__ __launch_bounds__(256) void remap_feat_k(const float* __restrict__ f,
        const int* __restrict__ perm, __bf16* __restrict__ out) {
    int p = blockIdx.x * 64 + (threadIdx.x >> 2);
    int j = threadIdx.x & 3;
    float4 v = ((const float4*)(f + (size_t)perm[p] * 16))[j];
    __bf16* dst = out + (size_t)p * 16 + j * 4;
    dst[0] = (__bf16)v.x; dst[1] = (__bf16)v.y; dst[2] = (__bf16)v.z; dst[3] = (__bf16)v.w;
}

// ------- fragmentized subm weights (CIN=64): wtf[k][ctg*KS+ks][lane][8] --------
template<int CIN, int KS>
__global__ __launch_bounds__(256) void frag_w_k(const float* __restrict__ w,
                                                __bf16* __restrict__ wtf) {
    int k = blockIdx.x;
    for (int idx = threadIdx.x; idx < 4 * KS * 512; idx += 256) {
        int j = idx & 7, l = (idx >> 3) & 63, f = idx >> 9;
        int ctg = f / KS, ks = f % KS;
        int co = ctg * 16 + (l & 15);
        int ci = ks * 32 + ((l >> 4) * 8) + j;
        float v = (ci < CIN) ? w[((size_t)k * CIN + ci) * 64 + co] : 0.f;
        wtf[((size_t)k * 4 * KS + f) * 512 + (idx & 511)] = (__bf16)v;
    }
}

// ------- paired layer-1 weights: offsets (2kp, 2kp+1) stacked in K=32 ----------
__global__ __launch_bounds__(256) void frag_w16p_k(const float* __restrict__ w,
                                                   __bf16* __restrict__ wtf) {
    int kp = blockIdx.x;   // 0..13
    for (int idx = threadIdx.x; idx < 4 * 512; idx += 256) {
        int j = idx & 7, l = (idx >> 3) & 63, f = idx >> 9;
        int co = f * 16 + (l & 15);
        int lg = l >> 4;
        int k = 2 * kp + (lg >> 1);
        int ci = (lg & 1) * 8 + j;
        float v = (k < 27) ? w[((size_t)k * 16 + ci) * 64 + co] : 0.f;
        wtf[((size_t)kp * 4 + f) * 512 + (idx & 511)] = (__bf16)v;
    }
}

// ------- conv weight transpose: OIHW (CO,64,5,5) f32 -> wt[k25][COPAD][64] bf16 -
template<int CO, int COPAD>
__global__ __launch_bounds__(256) void transpose_cw_k(const float* __restrict__ w,
                                                      __bf16* __restrict__ wt) {
    int k = blockIdx.x;  // 0..24
    for (int idx = threadIdx.x; idx < COPAD * 64; idx += 256) {
        int ci = idx & 63, co = idx >> 6;
        float v = (co < CO) ? w[((size_t)co * 64 + ci) * 25 + k] : 0.f;
        wt[((size_t)k * COPAD + co) * 64 + ci] = (__bf16)v;
    }
}

// ---------------- submanifold sparse conv: barrier-free direct-gather MFMA ------
// block = 4 waves = 128 points. Wave wid = points [wid*32,+32) x ALL 64 co.
// BOTH A and W explicitly double-buffered (distance-1 prefetch) so no WAR
// serialization on the W fragments; launch_bounds(256,2) gives the allocator
// room to keep both buffers live. No K-loop barriers.
template<int CIN, bool RELU>
__global__ __launch_bounds__(256, 2) void subm_mfma_k(
        const __bf16* __restrict__ feats,      // M x CIN (sorted)
        const int4* __restrict__ coords,       // M (sorted)
        const int* __restrict__ table,         // flat -> sorted row+1
        const __bf16* __restrict__ wtf,        // fragmentized weights
        const float* __restrict__ bias,
        __bf16* __restrict__ outp,
        const __bf16* __restrict__ zp) {       // 256B zero page
    constexpr int KS = (CIN == 64) ? 2 : 1;
    constexpr int PH = (CIN == 64) ? 27 : 14;
    __shared__ int rows_lds[28][128];

    const int tid = threadIdx.x, lane = tid & 63, wid = tid >> 6;
    const int lr = lane & 15, lg = lane >> 4;
    const int p0 = blockIdx.x * 128;

    // prologue: rows for this block's 128 points -> LDS (one barrier total)
    if (wid < 2) {
        int4 c4 = coords[p0 + wid * 64 + lane];
        const int px = c4.y, py = c4.z, pz = c4.w;
        #pragma unroll
        for (int k = 0; k < 27; ++k) {
            const int nx = px + k / 9 - 1, ny = py + (k / 3) % 3 - 1, nz = pz + k % 3 - 1;
            const bool v = ((unsigned)nx < NXD) & ((unsigned)ny < NYD) & ((unsigned)nz < NZD);
            rows_lds[k][wid * 64 + lane] = v ? table[(nx * NYD + ny) * NZD + nz] : 0;
        }
        rows_lds[27][wid * 64 + lane] = 0;
    }
    __syncthreads();

    f32x4 acc[2][4];
    #pragma unroll
    for (int ct = 0; ct < 4; ++ct) {
        float b = bias[ct * 16 + lr];
        #pragma unroll
        for (int pt = 0; pt < 2; ++pt) acc[pt][ct] = f32x4{b, b, b, b};
    }

    auto LOADA = [&](int p, bf16x8 (&a)[2][KS], int& sm) {
        if (p >= PH) return;
        sm = 0;
        #pragma unroll
        for (int pt = 0; pt < 2; ++pt) {
            const int kk = (CIN == 64) ? p : (2 * p + (lg >> 1));
            int srow = rows_lds[kk][wid * 32 + pt * 16 + lr];
            unsigned long long bm = __ballot(srow != 0);
            if (bm) {
                sm |= 1 << pt;
                if (CIN == 64) {
                    const __bf16* ab = (srow > 0) ? feats + (size_t)(srow - 1) * 64 : zp;
                    #pragma unroll
                    for (int ks = 0; ks < KS; ++ks)
                        a[pt][ks] = *(const bf16x8*)(ab + ks * 32 + lg * 8);
                } else {
                    const __bf16* ab = (srow > 0)
                        ? feats + (size_t)(srow - 1) * 16 + (lg & 1) * 8 : zp;
                    a[pt][0] = *(const bf16x8*)(ab);
                }
            }
        }
    };
    auto LOADW = [&](int p, bf16x8 (&w)[4][KS]) {
        if (p >= PH) return;
        #pragma unroll
        for (int ct = 0; ct < 4; ++ct)
            #pragma unroll
            for (int ks = 0; ks < KS; ++ks)
                w[ct][ks] = *(const bf16x8*)(wtf +
                    ((size_t)(p * 4 + ct) * KS + ks) * 512 + lane * 8);
    };
    auto MMAK = [&](bf16x8 (&a)[2][KS], bf16x8 (&w)[4][KS], int sm) {
        __builtin_amdgcn_s_setprio(1);
        #pragma unroll
        for (int pt = 0; pt < 2; ++pt)
            if (sm & (1 << pt))
                #pragma unroll
                for (int ct = 0; ct < 4; ++ct)
                    #pragma unroll
                    for (int ks = 0; ks < KS; ++ks)
                        acc[pt][ct] = __builtin_amdgcn_mfma_f32_16x16x32_bf16(
                            a[pt][ks], w[ct][ks], acc[pt][ct], 0, 0, 0);
        __builtin_amdgcn_s_setprio(0);
    };

    bf16x8 aX[2][KS], aY[2][KS], wA[4][KS], wB[4][KS];
    int smX = 0, smY = 0;
    LOADA(0, aX, smX);
    LOADW(0, wA);
    #pragma unroll 1
    for (int p = 0; p < PH; p += 2) {
        LOADA(p + 1, aY, smY);          // A for p+1 in flight during phase p
        LOADW(p + 1, wB);               // W for p+1 in flight (distinct regs!)
        MMAK(aX, wA, smX);              // phase p
        LOADA(p + 2, aX, smX);          // A for p+2
        LOADW(p + 2, wA);               // W for p+2
        if (p + 1 < PH) MMAK(aY, wB, smY);   // phase p+1
    }

    // epilogue: D col(lr)=co-in-tile, row(lg*4+r)=point-in-tile
    #pragma unroll
    for (int pt = 0; pt < 2; ++pt)
        #pragma unroll
        for (int ct = 0; ct < 4; ++ct) {
            const int co = ct * 16 + lr;
            #pragma unroll
            for (int r = 0; r < 4; ++r) {
                int p = p0 + wid * 32 + pt * 16 + lg * 4 + r;
                float v = acc[pt][ct][r];
                if (RELU) v = fmaxf(v, 0.f);
                outp[(size_t)p * 64 + co] = (__bf16)v;
            }
        }
}

// ---------------- BEV segment max (bf16 in, sorted rows) -> bf16 NHWC -----------
__global__ __launch_bounds__(256) void bev_max_k(const __bf16* __restrict__ h,
        const int* __restrict__ table, __bf16* __restrict__ bev) {
    int cell = blockIdx.x * 4 + (threadIdx.x >> 6);
    int lane = threadIdx.x & 63;
    int r = table[cell * 64 + lane];          // z = lane (NZ==64)
    float acc = -INFINITY;
    #pragma unroll 1
    for (int z = 0; z < 64; ++z) {
        int row = __shfl(r, z, 64);           // wave-uniform
        if (row > 0) acc = fmaxf(acc, (float)h[(size_t)(row - 1) * 64 + lane]);
    }
    bev[(size_t)cell * 64 + lane] = (__bf16)((acc == -INFINITY) ? 0.f : acc);
}

// ---------------- dense 5x5 conv via MFMA, NHWC bf16 in/out ---------------------
// 16x8 pixel tile per block (512 blocks).
template<bool RELU, bool FUSE_PW>
__global__ __launch_bounds__(256) void conv5_mfma_k(
        const __bf16* __restrict__ in,     // NHWC [NCELL][64]
        const __bf16* __restrict__ wtc,    // [25][64][64]
        const float* __restrict__ bias,    // [64]
        const __bf16* __restrict__ xres,   // NHWC (residual input, FUSE_PW)
        const __bf16* __restrict__ wpw,    // [64][64]
        const float* __restrict__ bpw,     // [64]
        __bf16* __restrict__ out) {        // NHWC
    __shared__ __bf16 halo[240 * 64];      // 12 rows x 20 cols, 30 KB
    __shared__ __bf16 xt[128 * 64];        // 16 KB (used when FUSE_PW)

    const int tid = threadIdx.x;
    const int gx0 = (blockIdx.x & 15) * 16;
    const int gy0 = (blockIdx.x >> 4) * 8;

    for (int i = tid; i < 1920; i += 256) {
        int hp = i >> 3, ch = i & 7;
        int hy = hp / 20, hx = hp - hy * 20;
        int gy = gy0 - 2 + hy, gx = gx0 - 2 + hx;
        uint4 v = {0, 0, 0, 0};
        if (gy >= 0 && gy < NXD && gx >= 0 && gx < NYD)
            v = *(const uint4*)(in + (((size_t)(gy << 8) + gx) << 6) + ch * 8);
        *(uint4*)((char*)halo + hp * 128 + ((ch ^ (hp & 7)) << 4)) = v;
    }
    if (FUSE_PW) {
        for (int i = tid; i < 1024; i += 256) {
            int p = i >> 3, ch = i & 7;
            int gy = gy0 + (p >> 4), gx = gx0 + (p & 15);
            uint4 v = *(const uint4*)(xres + (((size_t)(gy << 8) + gx) << 6) + ch * 8);
            *(uint4*)((char*)xt + p * 128 + ((ch ^ (p & 7)) << 4)) = v;
        }
    }
    __syncthreads();

    const int lane = tid & 63, wid = tid >> 6;
    const int lr = lane & 15, lg = lane >> 4;
    const int co = wid * 16 + lr;

    f32x4 acc[8];
    {
        float b = bias[co] + (FUSE_PW ? bpw[co] : 0.f);
        #pragma unroll
        for (int pt = 0; pt < 8; ++pt) acc[pt] = f32x4{b, b, b, b};
    }

    #pragma unroll 1
    for (int k = 0; k < 25; ++k) {
        const int dy = k / 5, dx = k - dy * 5;
        const __bf16* wrow = wtc + ((size_t)k * 64 + co) * 64 + lg * 8;
        bf16x8 bf0 = *(const bf16x8*)wrow;
        bf16x8 bf1 = *(const bf16x8*)(wrow + 32);
        #pragma unroll
        for (int pt = 0; pt < 8; ++pt) {
            int hp = (pt + dy) * 20 + lr + dx;
            bf16x8 a0 = *(const bf16x8*)((char*)halo + hp * 128 + ((lg ^ (hp & 7)) << 4));
            bf16x8 a1 = *(const bf16x8*)((char*)halo + hp * 128 + (((4 + lg) ^ (hp & 7)) << 4));
            acc[pt] = __builtin_amdgcn_mfma_f32_16x16x32_bf16(a0, bf0, acc[pt], 0, 0, 0);
            acc[pt] = __builtin_amdgcn_mfma_f32_16x16x32_bf16(a1, bf1, acc[pt], 0, 0, 0);
        }
    }
    if (FUSE_PW) {
        const __bf16* wrow = wpw + (size_t)co * 64 + lg * 8;
        bf16x8 bf0 = *(const bf16x8*)wrow;
        bf16x8 bf1 = *(const bf16x8*)(wrow + 32);
        #pragma unroll
        for (int pt = 0; pt < 8; ++pt) {
            int p = pt * 16 + lr;
            bf16x8 a0 = *(const bf16x8*)((char*)xt + p * 128 + ((lg ^ (p & 7)) << 4));
            bf16x8 a1 = *(const bf16x8*)((char*)xt + p * 128 + (((4 + lg) ^ (p & 7)) << 4));
            acc[pt] = __builtin_amdgcn_mfma_f32_16x16x32_bf16(a0, bf0, acc[pt], 0, 0, 0);
            acc[pt] = __builtin_amdgcn_mfma_f32_16x16x32_bf16(a1, bf1, acc[pt], 0, 0, 0);
        }
    }

    #pragma unroll
    for (int pt = 0; pt < 8; ++pt) {
        int gy = gy0 + pt;
        #pragma unroll
        for (int r = 0; r < 4; ++r) {
            int gx = gx0 + lg * 4 + r;
            float v = acc[pt][r];
            if (RELU) v = fmaxf(v, 0.f);
            out[(((size_t)(gy << 8) + gx) << 6) + co] = (__bf16)v;
        }
    }
}

// ---------------- dense 5x5 conv 64 -> 3 (co padded to 16), f32 planar out ------
__global__ __launch_bounds__(256) void conv5_mfma3_k(
        const __bf16* __restrict__ in,     // NHWC [NCELL][64]
        const __bf16* __restrict__ wtc,    // [25][16][64] (co padded)
        const float* __restrict__ bias3,   // [3]
        float* __restrict__ out) {         // planar [3][NCELL]
    __shared__ __bf16 halo[240 * 64];      // 12 rows x 20 cols, 30 KB

    const int tid = threadIdx.x;
    const int gx0 = (blockIdx.x & 15) * 16;
    const int gy0 = (blockIdx.x >> 4) * 8;

    for (int i = tid; i < 1920; i += 256) {
        int hp = i >> 3, ch = i & 7;
        int hy = hp / 20, hx = hp - hy * 20;
        int gy = gy0 - 2 + hy, gx = gx0 - 2 + hx;
        uint4 v = {0, 0, 0, 0};
        if (gy >= 0 && gy < NXD && gx >= 0 && gx < NYD)
            v = *(const uint4*)(in + (((size_t)(gy << 8) + gx) << 6) + ch * 8);
        *(uint4*)((char*)halo + hp * 128 + ((ch ^ (hp & 7)) << 4)) = v;
    }
    __syncthreads();

    const int lane = tid & 63, wid = tid >> 6;
    const int lr = lane & 15, lg = lane >> 4;

    f32x4 acc[2];
    {
        float b = (lr < 3) ? bias3[lr] : 0.f;
        #pragma unroll
        for (int t = 0; t < 2; ++t) acc[t] = f32x4{b, b, b, b};
    }

    #pragma unroll 1
    for (int k = 0; k < 25; ++k) {
        const int dy = k / 5, dx = k - dy * 5;
        const __bf16* wrow = wtc + ((size_t)k * 16 + lr) * 64 + lg * 8;
        bf16x8 bf0 = *(const bf16x8*)wrow;
        bf16x8 bf1 = *(const bf16x8*)(wrow + 32);
        #pragma unroll
        for (int t = 0; t < 2; ++t) {
            int pt = wid * 2 + t;
            int hp = (pt + dy) * 20 + lr + dx;
            bf16x8 a0 = *(const bf16x8*)((char*)halo + hp * 128 + ((lg ^ (hp & 7)) << 4));
            bf16x8 a1 = *(const bf16x8*)((char*)halo + hp * 128 + (((4 + lg) ^ (hp & 7)) << 4));
            acc[t] = __builtin_amdgcn_mfma_f32_16x16x32_bf16(a0, bf0, acc[t], 0, 0, 0);
            acc[t] = __builtin_amdgcn_mfma_f32_16x16x32_bf16(a1, bf1, acc[t], 0, 0, 0);
        }
    }

    if (lr < 3) {
        #pragma unroll
        for (int t = 0; t < 2; ++t) {
            int gy = gy0 + wid * 2 + t;
            #pragma unroll
            for (int r = 0; r < 4; ++r) {
                int gx = gx0 + lg * 4 + r;
                out[(size_t)lr * NCELL + (gy << 8) + gx] = fmaxf(acc[t][r], 0.f);
            }
        }
    }
}

// ---------------- dense 5x5 conv, scalar (3->3 only), f32 planar ----------------
template<int CIN, int COB, bool RELU>
__global__ __launch_bounds__(256) void conv5_k(const float* __restrict__ in,
        const float* __restrict__ w, const float* __restrict__ bias,
        float* __restrict__ out) {
    __shared__ float tile[20][20];
    int tid = threadIdx.x;
    int tx = tid & 15, ty = tid >> 4;
    int gx0 = blockIdx.x * 16 - 2, gy0 = blockIdx.y * 16 - 2;
    int co_base = blockIdx.z * COB;
    float acc[COB];
    #pragma unroll
    for (int i = 0; i < COB; ++i) acc[i] = bias[co_base + i];

    #pragma unroll 1
    for (int ci = 0; ci < CIN; ++ci) {
        __syncthreads();
        for (int idx = tid; idx < 400; idx += 256) {
            int r = idx / 20, cc = idx % 20;
            int sy = gy0 + r, sx = gx0 + cc;
            float v = 0.f;
            if (sy >= 0 && sy < NXD && sx >= 0 && sx < NYD)
                v = in[(size_t)ci * NCELL + sy * NYD + sx];
            tile[r][cc] = v;
        }
        __syncthreads();
        const float* wrow = w + ((size_t)co_base * CIN + ci) * 25;
        #pragma unroll
        for (int dy = 0; dy < 5; ++dy)
        #pragma unroll
        for (int dx = 0; dx < 5; ++dx) {
            float iv = tile[ty + dy][tx + dx];
            #pragma unroll
            for (int co = 0; co < COB; ++co)
                acc[co] = fmaf(iv, wrow[(size_t)co * CIN * 25 + dy * 5 + dx], acc[co]);
        }
    }
    int gy = gy0 + 2 + ty, gx = gx0 + 2 + tx;
    #pragma unroll
    for (int co = 0; co < COB; ++co) {
        float v = acc[co];
        if (RELU) v = fmaxf(v, 0.f);
        out[(size_t)(co_base + co) * NCELL + gy * NYD + gx] = v;
    }
}

// ---------------- final pointwise 64->3 + residual + relu + NHWC write ----------
__global__ __launch_bounds__(256) void pw_final_k(const __bf16* __restrict__ x,
        const float* __restrict__ pw, const float* __restrict__ pb,
        const float* __restrict__ h2, float* __restrict__ out) {
    int pix = blockIdx.x * 256 + threadIdx.x;
    float acc[3];
    #pragma unroll
    for (int co = 0; co < 3; ++co) acc[co] = pb[co] + h2[(size_t)co * NCELL + pix];
    const bf16x8* xr = (const bf16x8*)(x + (size_t)pix * 64);
    #pragma unroll
    for (int j = 0; j < 8; ++j) {
        bf16x8 v8 = xr[j];
        #pragma unroll
        for (int e = 0; e < 8; ++e) {
            float v = (float)v8[e];
            int ci = j * 8 + e;
            #pragma unroll
            for (int co = 0; co < 3; ++co) acc[co] = fmaf(v, pw[co * 64 + ci], acc[co]);
        }
    }
    #pragma unroll
    for (int co = 0; co < 3; ++co) out[(size_t)pix * 3 + co] = fmaxf(acc[co], 0.f);
}

extern "C" void kernel_launch(void* const* d_in, const int* in_sizes, int n_in,
                              void* d_out, int out_size, void* d_ws, size_t ws_size,
                              hipStream_t stream) {
    const float* features = (const float*)d_in[0];
    const float* w1   = (const float*)d_in[1];
    const float* b1   = (const float*)d_in[2];
    const float* w2   = (const float*)d_in[3];
    const float* b2   = (const float*)d_in[4];
    const float* w3   = (const float*)d_in[5];
    const float* b3   = (const float*)d_in[6];
    const float* cw11 = (const float*)d_in[7];
    const float* cb11 = (const float*)d_in[8];
    const float* cw12 = (const float*)d_in[9];
    const float* cb12 = (const float*)d_in[10];
    const float* cpw1 = (const float*)d_in[11];
    const float* cpb1 = (const float*)d_in[12];
    const float* cw21 = (const float*)d_in[13];
    const float* cb21 = (const float*)d_in[14];
    const float* cw22 = (const float*)d_in[15];
    const float* cb22 = (const float*)d_in[16];
    const float* cpw2 = (const float*)d_in[17];
    const float* cpb2 = (const float*)d_in[18];
    const int* table   = (const int*)d_in[20];
    const int M = in_sizes[0] / 16;   // 400000 (divisible by 128)

    // workspace layout (bytes)
    char* ws = (char*)d_ws;
    __bf16* A_bf    = (__bf16*)(ws);                    // M x 64 bf16
    __bf16* B_bf    = (__bf16*)(ws +  51200000ull);     // M x 64 bf16
    __bf16* feat_s  = (__bf16*)(ws + 102400000ull);     // M x 16 bf16 sorted
    __bf16* C_bf    = (__bf16*)(ws + 102400000ull);     // M x 64 bf16 (overlaps feat_s)
    int4*   coords  = (int4*)  (ws + 153600000ull);     // M x int4 (sorted)
    int*    table2  = (int*)   (ws + 160000000ull);     // 4.2M ints
    int*    perm    = (int*)   (ws + 176777216ull);     // M ints
    int*    partial = (int*)   (ws + 178377216ull);     // 4096 ints
    int*    scanned = (int*)   (ws + 178393600ull);     // 4096 ints
    __bf16* BEV     = (__bf16*)(ws + 204800000ull);     // [NCELL][64] bf16
    __bf16* H1      = (__bf16*)(ws + 213188608ull);     // [NCELL][64] bf16
    __bf16* T1      = (__bf16*)(ws + 221577216ull);     // [NCELL][64] bf16
    float*  S1      = (float*) (ws + 229965824ull);     // [3][NCELL]
    float*  S2      = (float*) (ws + 230752256ull);     // [3][NCELL]
    __bf16* WTC11   = (__bf16*)(ws + 232534016ull);     // 25x64x64
    __bf16* WTC12   = (__bf16*)(ws + 232738816ull);     // 25x64x64
    __bf16* WTC21   = (__bf16*)(ws + 232943616ull);     // 25x16x64
    __bf16* WPW1    = (__bf16*)(ws + 232994816ull);     // 64x64
    __bf16* WTF1    = (__bf16*)(ws + 233003008ull);     // 14x4x512 bf16 (paired)
    __bf16* WTF2    = (__bf16*)(ws + 233113600ull);     // 27x8x512 bf16
    __bf16* WTF3    = (__bf16*)(ws + 233334784ull);     // 27x8x512 bf16
    __bf16* ZP      = (__bf16*)(ws + 233555968ull);     // 256B zero page

    // ---- spatial sort (deterministic stream compaction of table) ----
    count_k<<<4096, 256, 0, stream>>>(table, partial);
    scan_k<<<1, 1024, 0, stream>>>(partial, scanned);
    emit_k<<<4096, 256, 0, stream>>>(table, scanned, table2, perm, coords);
    remap_feat_k<<<M / 64, 256, 0, stream>>>(features, perm, feat_s);

    zero_k<<<1, 64, 0, stream>>>((int*)ZP);
    f2bf_k<<<16, 256, 0, stream>>>(cpw1, WPW1, 4096);
    frag_w16p_k<<<14, 256, 0, stream>>>(w1, WTF1);
    frag_w_k<64, 2><<<27, 256, 0, stream>>>(w2, WTF2);
    frag_w_k<64, 2><<<27, 256, 0, stream>>>(w3, WTF3);
    transpose_cw_k<64, 64><<<25, 256, 0, stream>>>(cw11, WTC11);
    transpose_cw_k<64, 64><<<25, 256, 0, stream>>>(cw12, WTC12);
    transpose_cw_k<3, 16><<<25, 256, 0, stream>>>(cw21, WTC21);

    const int pblocks = M / 128;  // 3125
    subm_mfma_k<16, true ><<<pblocks, 256, 0, stream>>>(feat_s, coords, table2, WTF1, b1, A_bf, ZP);
    subm_mfma_k<64, true ><<<pblocks, 256, 0, stream>>>(A_bf,   coords, table2, WTF2, b2, B_bf, ZP);
    subm_mfma_k<64, false><<<pblocks, 256, 0, stream>>>(B_bf,   coords, table2, WTF3, b3, C_bf, ZP);

    bev_max_k<<<NCELL / 4, 256, 0, stream>>>(C_bf, table2, BEV);

    // resblock 1 (64ch): conv11 -> H1; conv12 + fused pw/residual -> T1
    conv5_mfma_k<true, false><<<512, 256, 0, stream>>>(BEV, WTC11, cb11, nullptr, nullptr, nullptr, H1);
    conv5_mfma_k<true, true ><<<512, 256, 0, stream>>>(H1, WTC12, cb12, BEV, WPW1, cpb1, T1);

    // resblock 2 (3ch): conv21 (relu) -> S1; conv22 3->3 -> S2; final pw+res+relu
    conv5_mfma3_k<<<512, 256, 0, stream>>>(T1, WTC21, cb21, S1);
    conv5_k<3, 3, false><<<dim3(16, 16, 1), 256, 0, stream>>>(S1, cw22, cb22, S2);
    pw_final_k<<<NCELL / 256, 256, 0, stream>>>(T1, cpw2, cpb2, S2, (float*)d_out);
}

// Round 13
// 520.788 us; speedup vs baseline: 1.1847x; 1.1847x over previous
//
#include <hip/hip_runtime.h>
#include <math.h>

#define NXD 256
#define NYD 256
#define NZD 64
#define NCELL (NXD*NYD)

typedef __bf16 bf16x8 __attribute__((ext_vector_type(8)));
typedef float f32x4 __attribute__((ext_vector_type(4)));

// ---------------- small utils ----------------
__global__ __launch_bounds__(64) void zero_k(int* p) { p[threadIdx.x] = 0; }

__global__ __launch_bounds__(256) void f2bf_k(const float* __restrict__ in,
                                              __bf16* __restrict__ out, int n) {
    int i = blockIdx.x * 256 + threadIdx.x;
    if (i < n) out[i] = (__bf16)in[i];
}

// ================= spatial sort (stream compaction of table) ===================
__global__ __launch_bounds__(256) void count_k(const int* __restrict__ table,
                                               int* __restrict__ partial) {
    __shared__ int red[4];
    int tid = threadIdx.x, lane = tid & 63, wid = tid >> 6;
    int4 v = *(const int4*)(table + blockIdx.x * 1024 + tid * 4);
    int c = (v.x > 0) + (v.y > 0) + (v.z > 0) + (v.w > 0);
    for (int d = 32; d; d >>= 1) c += __shfl_down(c, d, 64);
    if (lane == 0) red[wid] = c;
    __syncthreads();
    if (tid == 0) partial[blockIdx.x] = red[0] + red[1] + red[2] + red[3];
}

__global__ __launch_bounds__(1024) void scan_k(const int* __restrict__ partial,
                                               int* __restrict__ scanned) {
    __shared__ int wsum[16];
    int tid = threadIdx.x, lane = tid & 63, wid = tid >> 6;
    int4 v = ((const int4*)partial)[tid];
    int tot = v.x + v.y + v.z + v.w;
    int sc = tot;
    for (int d = 1; d < 64; d <<= 1) { int o = __shfl_up(sc, d, 64); if (lane >= d) sc += o; }
    if (lane == 63) wsum[wid] = sc;
    __syncthreads();
    int wbase = 0;
    for (int w = 0; w < 16; ++w) if (w < wid) wbase += wsum[w];
    int excl = wbase + sc - tot;
    int4 o4;
    o4.x = excl; o4.y = excl + v.x; o4.z = excl + v.x + v.y; o4.w = excl + v.x + v.y + v.z;
    ((int4*)scanned)[tid] = o4;
}

__global__ __launch_bounds__(256) void emit_k(const int* __restrict__ table,
        const int* __restrict__ scanned, int* __restrict__ table2,
        int* __restrict__ perm, int4* __restrict__ coords) {
    __shared__ int wsum[4];
    int tid = threadIdx.x, lane = tid & 63, wid = tid >> 6;
    int gbase = blockIdx.x * 1024 + tid * 4;
    int4 v = *(const int4*)(table + gbase);
    int vals[4] = {v.x, v.y, v.z, v.w};
    int c = (v.x > 0) + (v.y > 0) + (v.z > 0) + (v.w > 0);
    int sc = c;
    for (int d = 1; d < 64; d <<= 1) { int o = __shfl_up(sc, d, 64); if (lane >= d) sc += o; }
    if (lane == 63) wsum[wid] = sc;
    __syncthreads();
    int wbase = 0;
    for (int w = 0; w < 4; ++w) if (w < wid) wbase += wsum[w];
    int pos = scanned[blockIdx.x] + wbase + sc - c;
    int t2[4];
    #pragma unroll
    for (int j = 0; j < 4; ++j) {
        int flat = gbase + j;
        if (vals[j] > 0) {
            t2[j] = pos + 1;
            perm[pos] = vals[j] - 1;
            coords[pos] = make_int4(0, flat >> 14, (flat >> 6) & 255, flat & 63);
            ++pos;
        } else t2[j] = 0;
    }
    *(int4*)(table2 + gbase) = make_int4(t2[0], t2[1], t2[2], t2[3]);
}

__global__ __launch_bounds__(256) void remap_feat_k(const float* __restrict__ f,
        const int* __restrict__ perm, __bf16* __restrict__ out) {
    int p = blockIdx.x * 64 + (threadIdx.x >> 2);
    int j = threadIdx.x & 3;
    float4 v = ((const float4*)(f + (size_t)perm[p] * 16))[j];
    __bf16* dst = out + (size_t)p * 16 + j * 4;
    dst[0] = (__bf16)v.x; dst[1] = (__bf16)v.y; dst[2] = (__bf16)v.z; dst[3] = (__bf16)v.w;
}

// ------- fragmentized subm weights (CIN=64): wtf[k][ctg*KS+ks][lane][8] --------
template<int CIN, int KS>
__global__ __launch_bounds__(256) void frag_w_k(const float* __restrict__ w,
                                                __bf16* __restrict__ wtf) {
    int k = blockIdx.x;
    for (int idx = threadIdx.x; idx < 4 * KS * 512; idx += 256) {
        int j = idx & 7, l = (idx >> 3) & 63, f = idx >> 9;
        int ctg = f / KS, ks = f % KS;
        int co = ctg * 16 + (l & 15);
        int ci = ks * 32 + ((l >> 4) * 8) + j;
        float v = (ci < CIN) ? w[((size_t)k * CIN + ci) * 64 + co] : 0.f;
        wtf[((size_t)k * 4 * KS + f) * 512 + (idx & 511)] = (__bf16)v;
    }
}

// ------- paired layer-1 weights: offsets (2kp, 2kp+1) stacked in K=32 ----------
__global__ __launch_bounds__(256) void frag_w16p_k(const float* __restrict__ w,
                                                   __bf16* __restrict__ wtf) {
    int kp = blockIdx.x;   // 0..13
    for (int idx = threadIdx.x; idx < 4 * 512; idx += 256) {
        int j = idx & 7, l = (idx >> 3) & 63, f = idx >> 9;
        int co = f * 16 + (l & 15);
        int lg = l >> 4;
        int k = 2 * kp + (lg >> 1);
        int ci = (lg & 1) * 8 + j;
        float v = (k < 27) ? w[((size_t)k * 16 + ci) * 64 + co] : 0.f;
        wtf[((size_t)kp * 4 + f) * 512 + (idx & 511)] = (__bf16)v;
    }
}

// ------- conv weight transpose: OIHW (CO,64,5,5) f32 -> wt[k25][COPAD][64] bf16 -
template<int CO, int COPAD>
__global__ __launch_bounds__(256) void transpose_cw_k(const float* __restrict__ w,
                                                      __bf16* __restrict__ wt) {
    int k = blockIdx.x;  // 0..24
    for (int idx = threadIdx.x; idx < COPAD * 64; idx += 256) {
        int ci = idx & 63, co = idx >> 6;
        float v = (co < CO) ? w[((size_t)co * 64 + ci) * 25 + k] : 0.f;
        wt[((size_t)k * COPAD + co) * 64 + ci] = (__bf16)v;
    }
}

// ---------------- submanifold sparse conv: barrier-free direct-gather MFMA ------
// (round-11 structure -- measured best: subm64 164.7us, occ 37.9%)
// block = 4 waves = 128 points. Wave wid = points [wid*32,+32) x ALL 64 co.
// A-prefetch distance 2 (triple buffer); W single-buffer JIT. No K-loop barriers.
template<int CIN, bool RELU>
__global__ __launch_bounds__(256) void subm_mfma_k(
        const __bf16* __restrict__ feats,      // M x CIN (sorted)
        const int4* __restrict__ coords,       // M (sorted)
        const int* __restrict__ table,         // flat -> sorted row+1
        const __bf16* __restrict__ wtf,        // fragmentized weights
        const float* __restrict__ bias,
        __bf16* __restrict__ outp,
        const __bf16* __restrict__ zp) {       // 256B zero page
    constexpr int KS = (CIN == 64) ? 2 : 1;
    constexpr int PH = (CIN == 64) ? 27 : 14;
    __shared__ int rows_lds[28][128];

    const int tid = threadIdx.x, lane = tid & 63, wid = tid >> 6;
    const int lr = lane & 15, lg = lane >> 4;
    const int p0 = blockIdx.x * 128;

    // prologue: rows for this block's 128 points -> LDS (one barrier total)
    if (wid < 2) {
        int4 c4 = coords[p0 + wid * 64 + lane];
        const int px = c4.y, py = c4.z, pz = c4.w;
        #pragma unroll
        for (int k = 0; k < 27; ++k) {
            const int nx = px + k / 9 - 1, ny = py + (k / 3) % 3 - 1, nz = pz + k % 3 - 1;
            const bool v = ((unsigned)nx < NXD) & ((unsigned)ny < NYD) & ((unsigned)nz < NZD);
            rows_lds[k][wid * 64 + lane] = v ? table[(nx * NYD + ny) * NZD + nz] : 0;
        }
        rows_lds[27][wid * 64 + lane] = 0;
    }
    __syncthreads();

    f32x4 acc[2][4];
    #pragma unroll
    for (int ct = 0; ct < 4; ++ct) {
        float b = bias[ct * 16 + lr];
        #pragma unroll
        for (int pt = 0; pt < 2; ++pt) acc[pt][ct] = f32x4{b, b, b, b};
    }

    auto LOADA = [&](int p, bf16x8 (&a)[2][KS], int& sm) {
        if (p >= PH) return;
        sm = 0;
        #pragma unroll
        for (int pt = 0; pt < 2; ++pt) {
            const int kk = (CIN == 64) ? p : (2 * p + (lg >> 1));
            int srow = rows_lds[kk][wid * 32 + pt * 16 + lr];
            unsigned long long bm = __ballot(srow != 0);
            if (bm) {
                sm |= 1 << pt;
                if (CIN == 64) {
                    const __bf16* ab = (srow > 0) ? feats + (size_t)(srow - 1) * 64 : zp;
                    #pragma unroll
                    for (int ks = 0; ks < KS; ++ks)
                        a[pt][ks] = *(const bf16x8*)(ab + ks * 32 + lg * 8);
                } else {
                    const __bf16* ab = (srow > 0)
                        ? feats + (size_t)(srow - 1) * 16 + (lg & 1) * 8 : zp;
                    a[pt][0] = *(const bf16x8*)ab;
                }
            }
        }
    };
    auto LOADW = [&](int p, bf16x8 (&w)[4][KS]) {
        #pragma unroll
        for (int ct = 0; ct < 4; ++ct)
            #pragma unroll
            for (int ks = 0; ks < KS; ++ks)
                w[ct][ks] = *(const bf16x8*)(wtf +
                    ((size_t)(p * 4 + ct) * KS + ks) * 512 + lane * 8);
    };
    auto MMAK = [&](bf16x8 (&a)[2][KS], bf16x8 (&w)[4][KS], int sm) {
        __builtin_amdgcn_s_setprio(1);
        #pragma unroll
        for (int pt = 0; pt < 2; ++pt)
            if (sm & (1 << pt))
                #pragma unroll
                for (int ct = 0; ct < 4; ++ct)
                    #pragma unroll
                    for (int ks = 0; ks < KS; ++ks)
                        acc[pt][ct] = __builtin_amdgcn_mfma_f32_16x16x32_bf16(
                            a[pt][ks], w[ct][ks], acc[pt][ct], 0, 0, 0);
        __builtin_amdgcn_s_setprio(0);
    };

    bf16x8 aX[2][KS], aY[2][KS], aZ[2][KS], wU[4][KS];
    int smX = 0, smY = 0, smZ = 0;
    LOADA(0, aX, smX);
    LOADA(1, aY, smY);
    #pragma unroll 1
    for (int p = 0; p < PH; p += 3) {
        LOADW(p, wU);
        LOADA(p + 2, aZ, smZ);
        MMAK(aX, wU, smX);
        if (p + 1 < PH) {
            LOADW(p + 1, wU);
            LOADA(p + 3, aX, smX);
            MMAK(aY, wU, smY);
        }
        if (p + 2 < PH) {
            LOADW(p + 2, wU);
            LOADA(p + 4, aY, smY);
            MMAK(aZ, wU, smZ);
        }
    }

    // epilogue: D col(lr)=co-in-tile, row(lg*4+r)=point-in-tile
    #pragma unroll
    for (int pt = 0; pt < 2; ++pt)
        #pragma unroll
        for (int ct = 0; ct < 4; ++ct) {
            const int co = ct * 16 + lr;
            #pragma unroll
            for (int r = 0; r < 4; ++r) {
                int p = p0 + wid * 32 + pt * 16 + lg * 4 + r;
                float v = acc[pt][ct][r];
                if (RELU) v = fmaxf(v, 0.f);
                outp[(size_t)p * 64 + co] = (__bf16)v;
            }
        }
}

// ---------------- BEV segment max (bf16 in, sorted rows) -> bf16 NHWC -----------
// ballot-skip: iterate only occupied z slots (~6.1 avg of 64).
__global__ __launch_bounds__(256) void bev_max_k(const __bf16* __restrict__ h,
        const int* __restrict__ table, __bf16* __restrict__ bev) {
    int cell = blockIdx.x * 4 + (threadIdx.x >> 6);
    int lane = threadIdx.x & 63;
    int r = table[cell * 64 + lane];          // z = lane (NZ==64)
    unsigned long long mask = __ballot(r > 0);   // wave-uniform
    float acc = -INFINITY;
    while (mask) {
        int z = __ffsll((unsigned long long)mask) - 1;
        mask &= mask - 1;
        int row = __shfl(r, z, 64);           // wave-uniform
        acc = fmaxf(acc, (float)h[(size_t)(row - 1) * 64 + lane]);
    }
    bev[(size_t)cell * 64 + lane] = (__bf16)((acc == -INFINITY) ? 0.f : acc);
}

// ---------------- dense 5x5 conv via MFMA, NHWC bf16 in/out ---------------------
// 16x8 pixel tile per block (512 blocks).
template<bool RELU, bool FUSE_PW>
__global__ __launch_bounds__(256) void conv5_mfma_k(
        const __bf16* __restrict__ in,     // NHWC [NCELL][64]
        const __bf16* __restrict__ wtc,    // [25][64][64]
        const float* __restrict__ bias,    // [64]
        const __bf16* __restrict__ xres,   // NHWC (residual input, FUSE_PW)
        const __bf16* __restrict__ wpw,    // [64][64]
        const float* __restrict__ bpw,     // [64]
        __bf16* __restrict__ out) {        // NHWC
    __shared__ __bf16 halo[240 * 64];      // 12 rows x 20 cols, 30 KB
    __shared__ __bf16 xt[128 * 64];        // 16 KB (used when FUSE_PW)

    const int tid = threadIdx.x;
    const int gx0 = (blockIdx.x & 15) * 16;
    const int gy0 = (blockIdx.x >> 4) * 8;

    for (int i = tid; i < 1920; i += 256) {
        int hp = i >> 3, ch = i & 7;
        int hy = hp / 20, hx = hp - hy * 20;
        int gy = gy0 - 2 + hy, gx = gx0 - 2 + hx;
        uint4 v = {0, 0, 0, 0};
        if (gy >= 0 && gy < NXD && gx >= 0 && gx < NYD)
            v = *(const uint4*)(in + (((size_t)(gy << 8) + gx) << 6) + ch * 8);
        *(uint4*)((char*)halo + hp * 128 + ((ch ^ (hp & 7)) << 4)) = v;
    }
    if (FUSE_PW) {
        for (int i = tid; i < 1024; i += 256) {
            int p = i >> 3, ch = i & 7;
            int gy = gy0 + (p >> 4), gx = gx0 + (p & 15);
            uint4 v = *(const uint4*)(xres + (((size_t)(gy << 8) + gx) << 6) + ch * 8);
            *(uint4*)((char*)xt + p * 128 + ((ch ^ (p & 7)) << 4)) = v;
        }
    }
    __syncthreads();

    const int lane = tid & 63, wid = tid >> 6;
    const int lr = lane & 15, lg = lane >> 4;
    const int co = wid * 16 + lr;

    f32x4 acc[8];
    {
        float b = bias[co] + (FUSE_PW ? bpw[co] : 0.f);
        #pragma unroll
        for (int pt = 0; pt < 8; ++pt) acc[pt] = f32x4{b, b, b, b};
    }

    #pragma unroll 1
    for (int k = 0; k < 25; ++k) {
        const int dy = k / 5, dx = k - dy * 5;
        const __bf16* wrow = wtc + ((size_t)k * 64 + co) * 64 + lg * 8;
        bf16x8 bf0 = *(const bf16x8*)wrow;
        bf16x8 bf1 = *(const bf16x8*)(wrow + 32);
        #pragma unroll
        for (int pt = 0; pt < 8; ++pt) {
            int hp = (pt + dy) * 20 + lr + dx;
            bf16x8 a0 = *(const bf16x8*)((char*)halo + hp * 128 + ((lg ^ (hp & 7)) << 4));
            bf16x8 a1 = *(const bf16x8*)((char*)halo + hp * 128 + (((4 + lg) ^ (hp & 7)) << 4));
            acc[pt] = __builtin_amdgcn_mfma_f32_16x16x32_bf16(a0, bf0, acc[pt], 0, 0, 0);
            acc[pt] = __builtin_amdgcn_mfma_f32_16x16x32_bf16(a1, bf1, acc[pt], 0, 0, 0);
        }
    }
    if (FUSE_PW) {
        const __bf16* wrow = wpw + (size_t)co * 64 + lg * 8;
        bf16x8 bf0 = *(const bf16x8*)wrow;
        bf16x8 bf1 = *(const bf16x8*)(wrow + 32);
        #pragma unroll
        for (int pt = 0; pt < 8; ++pt) {
            int p = pt * 16 + lr;
            bf16x8 a0 = *(const bf16x8*)((char*)xt + p * 128 + ((lg ^ (p & 7)) << 4));
            bf16x8 a1 = *(const bf16x8*)((char*)xt + p * 128 + (((4 + lg) ^ (p & 7)) << 4));
            acc[pt] = __builtin_amdgcn_mfma_f32_16x16x32_bf16(a0, bf0, acc[pt], 0, 0, 0);
            acc[pt] = __builtin_amdgcn_mfma_f32_16x16x32_bf16(a1, bf1, acc[pt], 0, 0, 0);
        }
    }

    #pragma unroll
    for (int pt = 0; pt < 8; ++pt) {
        int gy = gy0 + pt;
        #pragma unroll
        for (int r = 0; r < 4; ++r) {
            int gx = gx0 + lg * 4 + r;
            float v = acc[pt][r];
            if (RELU) v = fmaxf(v, 0.f);
            out[(((size_t)(gy << 8) + gx) << 6) + co] = (__bf16)v;
        }
    }
}

// ---------------- dense 5x5 conv 64 -> 3 (co padded to 16), f32 planar out ------
__global__ __launch_bounds__(256) void conv5_mfma3_k(
        const __bf16* __restrict__ in,     // NHWC [NCELL][64]
        const __bf16* __restrict__ wtc,    // [25][16][64] (co padded)
        const float* __restrict__ bias3,   // [3]
        float* __restrict__ out) {         // planar [3][NCELL]
    __shared__ __bf16 halo[240 * 64];      // 12 rows x 20 cols, 30 KB

    const int tid = threadIdx.x;
    const int gx0 = (blockIdx.x & 15) * 16;
    const int gy0 = (blockIdx.x >> 4) * 8;

    for (int i = tid; i < 1920; i += 256) {
        int hp = i >> 3, ch = i & 7;
        int hy = hp / 20, hx = hp - hy * 20;
        int gy = gy0 - 2 + hy, gx = gx0 - 2 + hx;
        uint4 v = {0, 0, 0, 0};
        if (gy >= 0 && gy < NXD && gx >= 0 && gx < NYD)
            v = *(const uint4*)(in + (((size_t)(gy << 8) + gx) << 6) + ch * 8);
        *(uint4*)((char*)halo + hp * 128 + ((ch ^ (hp & 7)) << 4)) = v;
    }
    __syncthreads();

    const int lane = tid & 63, wid = tid >> 6;
    const int lr = lane & 15, lg = lane >> 4;

    f32x4 acc[2];
    {
        float b = (lr < 3) ? bias3[lr] : 0.f;
        #pragma unroll
        for (int t = 0; t < 2; ++t) acc[t] = f32x4{b, b, b, b};
    }

    #pragma unroll 1
    for (int k = 0; k < 25; ++k) {
        const int dy = k / 5, dx = k - dy * 5;
        const __bf16* wrow = wtc + ((size_t)k * 16 + lr) * 64 + lg * 8;
        bf16x8 bf0 = *(const bf16x8*)wrow;
        bf16x8 bf1 = *(const bf16x8*)(wrow + 32);
        #pragma unroll
        for (int t = 0; t < 2; ++t) {
            int pt = wid * 2 + t;
            int hp = (pt + dy) * 20 + lr + dx;
            bf16x8 a0 = *(const bf16x8*)((char*)halo + hp * 128 + ((lg ^ (hp & 7)) << 4));
            bf16x8 a1 = *(const bf16x8*)((char*)halo + hp * 128 + (((4 + lg) ^ (hp & 7)) << 4));
            acc[t] = __builtin_amdgcn_mfma_f32_16x16x32_bf16(a0, bf0, acc[t], 0, 0, 0);
            acc[t] = __builtin_amdgcn_mfma_f32_16x16x32_bf16(a1, bf1, acc[t], 0, 0, 0);
        }
    }

    if (lr < 3) {
        #pragma unroll
        for (int t = 0; t < 2; ++t) {
            int gy = gy0 + wid * 2 + t;
            #pragma unroll
            for (int r = 0; r < 4; ++r) {
                int gx = gx0 + lg * 4 + r;
                out[(size_t)lr * NCELL + (gy << 8) + gx] = fmaxf(acc[t][r], 0.f);
            }
        }
    }
}

// ---------------- dense 5x5 conv, scalar (3->3 only), f32 planar ----------------
template<int CIN, int COB, bool RELU>
__global__ __launch_bounds__(256) void conv5_k(const float* __restrict__ in,
        const float* __restrict__ w, const float* __restrict__ bias,
        float* __restrict__ out) {
    __shared__ float tile[20][20];
    int tid = threadIdx.x;
    int tx = tid & 15, ty = tid >> 4;
    int gx0 = blockIdx.x * 16 - 2, gy0 = blockIdx.y * 16 - 2;
    int co_base = blockIdx.z * COB;
    float acc[COB];
    #pragma unroll
    for (int i = 0; i < COB; ++i) acc[i] = bias[co_base + i];

    #pragma unroll 1
    for (int ci = 0; ci < CIN; ++ci) {
        __syncthreads();
        for (int idx = tid; idx < 400; idx += 256) {
            int r = idx / 20, cc = idx % 20;
            int sy = gy0 + r, sx = gx0 + cc;
            float v = 0.f;
            if (sy >= 0 && sy < NXD && sx >= 0 && sx < NYD)
                v = in[(size_t)ci * NCELL + sy * NYD + sx];
            tile[r][cc] = v;
        }
        __syncthreads();
        const float* wrow = w + ((size_t)co_base * CIN + ci) * 25;
        #pragma unroll
        for (int dy = 0; dy < 5; ++dy)
        #pragma unroll
        for (int dx = 0; dx < 5; ++dx) {
            float iv = tile[ty + dy][tx + dx];
            #pragma unroll
            for (int co = 0; co < COB; ++co)
                acc[co] = fmaf(iv, wrow[(size_t)co * CIN * 25 + dy * 5 + dx], acc[co]);
        }
    }
    int gy = gy0 + 2 + ty, gx = gx0 + 2 + tx;
    #pragma unroll
    for (int co = 0; co < COB; ++co) {
        float v = acc[co];
        if (RELU) v = fmaxf(v, 0.f);
        out[(size_t)(co_base + co) * NCELL + gy * NYD + gx] = v;
    }
}

// ---------------- final pointwise 64->3 + residual + relu + NHWC write ----------
__global__ __launch_bounds__(256) void pw_final_k(const __bf16* __restrict__ x,
        const float* __restrict__ pw, const float* __restrict__ pb,
        const float* __restrict__ h2, float* __restrict__ out) {
    int pix = blockIdx.x * 256 + threadIdx.x;
    float acc[3];
    #pragma unroll
    for (int co = 0; co < 3; ++co) acc[co] = pb[co] + h2[(size_t)co * NCELL + pix];
    const bf16x8* xr = (const bf16x8*)(x + (size_t)pix * 64);
    #pragma unroll
    for (int j = 0; j < 8; ++j) {
        bf16x8 v8 = xr[j];
        #pragma unroll
        for (int e = 0; e < 8; ++e) {
            float v = (float)v8[e];
            int ci = j * 8 + e;
            #pragma unroll
            for (int co = 0; co < 3; ++co) acc[co] = fmaf(v, pw[co * 64 + ci], acc[co]);
        }
    }
    #pragma unroll
    for (int co = 0; co < 3; ++co) out[(size_t)pix * 3 + co] = fmaxf(acc[co], 0.f);
}

extern "C" void kernel_launch(void* const* d_in, const int* in_sizes, int n_in,
                              void* d_out, int out_size, void* d_ws, size_t ws_size,
                              hipStream_t stream) {
    const float* features = (const float*)d_in[0];
    const float* w1   = (const float*)d_in[1];
    const float* b1   = (const float*)d_in[2];
    const float* w2   = (const float*)d_in[3];
    const float* b2   = (const float*)d_in[4];
    const float* w3   = (const float*)d_in[5];
    const float* b3   = (const float*)d_in[6];
    const float* cw11 = (const float*)d_in[7];
    const float* cb11 = (const float*)d_in[8];
    const float* cw12 = (const float*)d_in[9];
    const float* cb12 = (const float*)d_in[10];
    const float* cpw1 = (const float*)d_in[11];
    const float* cpb1 = (const float*)d_in[12];
    const float* cw21 = (const float*)d_in[13];
    const float* cb21 = (const float*)d_in[14];
    const float* cw22 = (const float*)d_in[15];
    const float* cb22 = (const float*)d_in[16];
    const float* cpw2 = (const float*)d_in[17];
    const float* cpb2 = (const float*)d_in[18];
    const int* table   = (const int*)d_in[20];
    const int M = in_sizes[0] / 16;   // 400000 (divisible by 128)

    // workspace layout (bytes)
    char* ws = (char*)d_ws;
    __bf16* A_bf    = (__bf16*)(ws);                    // M x 64 bf16
    __bf16* B_bf    = (__bf16*)(ws +  51200000ull);     // M x 64 bf16
    __bf16* feat_s  = (__bf16*)(ws + 102400000ull);     // M x 16 bf16 sorted
    __bf16* C_bf    = (__bf16*)(ws + 102400000ull);     // M x 64 bf16 (overlaps feat_s)
    int4*   coords  = (int4*)  (ws + 153600000ull);     // M x int4 (sorted)
    int*    table2  = (int*)   (ws + 160000000ull);     // 4.2M ints
    int*    perm    = (int*)   (ws + 176777216ull);     // M ints
    int*    partial = (int*)   (ws + 178377216ull);     // 4096 ints
    int*    scanned = (int*)   (ws + 178393600ull);     // 4096 ints
    __bf16* BEV     = (__bf16*)(ws + 204800000ull);     // [NCELL][64] bf16
    __bf16* H1      = (__bf16*)(ws + 213188608ull);     // [NCELL][64] bf16
    __bf16* T1      = (__bf16*)(ws + 221577216ull);     // [NCELL][64] bf16
    float*  S1      = (float*) (ws + 229965824ull);     // [3][NCELL]
    float*  S2      = (float*) (ws + 230752256ull);     // [3][NCELL]
    __bf16* WTC11   = (__bf16*)(ws + 232534016ull);     // 25x64x64
    __bf16* WTC12   = (__bf16*)(ws + 232738816ull);     // 25x64x64
    __bf16* WTC21   = (__bf16*)(ws + 232943616ull);     // 25x16x64
    __bf16* WPW1    = (__bf16*)(ws + 232994816ull);     // 64x64
    __bf16* WTF1    = (__bf16*)(ws + 233003008ull);     // 14x4x512 bf16 (paired)
    __bf16* WTF2    = (__bf16*)(ws + 233113600ull);     // 27x8x512 bf16
    __bf16* WTF3    = (__bf16*)(ws + 233334784ull);     // 27x8x512 bf16
    __bf16* ZP      = (__bf16*)(ws + 233555968ull);     // 256B zero page

    // ---- spatial sort (deterministic stream compaction of table) ----
    count_k<<<4096, 256, 0, stream>>>(table, partial);
    scan_k<<<1, 1024, 0, stream>>>(partial, scanned);
    emit_k<<<4096, 256, 0, stream>>>(table, scanned, table2, perm, coords);
    remap_feat_k<<<M / 64, 256, 0, stream>>>(features, perm, feat_s);

    zero_k<<<1, 64, 0, stream>>>((int*)ZP);
    f2bf_k<<<16, 256, 0, stream>>>(cpw1, WPW1, 4096);
    frag_w16p_k<<<14, 256, 0, stream>>>(w1, WTF1);
    frag_w_k<64, 2><<<27, 256, 0, stream>>>(w2, WTF2);
    frag_w_k<64, 2><<<27, 256, 0, stream>>>(w3, WTF3);
    transpose_cw_k<64, 64><<<25, 256, 0, stream>>>(cw11, WTC11);
    transpose_cw_k<64, 64><<<25, 256, 0, stream>>>(cw12, WTC12);
    transpose_cw_k<3, 16><<<25, 256, 0, stream>>>(cw21, WTC21);

    const int pblocks = M / 128;  // 3125
    subm_mfma_k<16, true ><<<pblocks, 256, 0, stream>>>(feat_s, coords, table2, WTF1, b1, A_bf, ZP);
    subm_mfma_k<64, true ><<<pblocks, 256, 0, stream>>>(A_bf,   coords, table2, WTF2, b2, B_bf, ZP);
    subm_mfma_k<64, false><<<pblocks, 256, 0, stream>>>(B_bf,   coords, table2, WTF3, b3, C_bf, ZP);

    bev_max_k<<<NCELL / 4, 256, 0, stream>>>(C_bf, table2, BEV);

    // resblock 1 (64ch): conv11 -> H1; conv12 + fused pw/residual -> T1
    conv5_mfma_k<true, false><<<512, 256, 0, stream>>>(BEV, WTC11, cb11, nullptr, nullptr, nullptr, H1);
    conv5_mfma_k<true, true ><<<512, 256, 0, stream>>>(H1, WTC12, cb12, BEV, WPW1, cpb1, T1);

    // resblock 2 (3ch): conv21 (relu) -> S1; conv22 3->3 -> S2; final pw+res+relu
    conv5_mfma3_k<<<512, 256, 0, stream>>>(T1, WTC21, cb21, S1);
    conv5_k<3, 3, false><<<dim3(16, 16, 1), 256, 0, stream>>>(S1, cw22, cb22, S2);
    pw_final_k<<<NCELL / 256, 256, 0, stream>>>(T1, cpw2, cpb2, S2, (float*)d_out);
}